// Round 6
// baseline (56.601 us; speedup 1.0000x reference)
//
#include <hip/hip_runtime.h>

#define EPSV 2.220446049250313e-16f
#define C3F  (-0.09016844005555896f)   // -log2(e)/16
#define SSCL 0.1201122408786449f       // sqrt(log2(e)/100); (SSCL*dI)^2 = dI^2*log2(e)/100

typedef float f2 __attribute__((ext_vector_type(2)));
typedef float f4 __attribute__((ext_vector_type(4)));

// batch: (8,1,32,32,32) f32 ; preds: (8,6,32,32,32) f32 ; out: (8,) f32
// PAD=3, WIN=7. w(p,off) = exp2(g - (s*dI)^2), g = -d2*log2e/16, zero outside ball d2<16.
// Grid: (b,d,dz) = 1792 blocks, 512 threads.
// Thread = (kh, row, voxel-quad): kh = tid>>8 -> classes 3*kh..3*kh+2; 4 voxels each.

__global__ __launch_bounds__(512, 6) void ncut_main(const float* __restrict__ batch,
                                                    const float* __restrict__ preds,
                                                    float* __restrict__ wsA,
                                                    float* __restrict__ wsV) {
    constexpr int LS = 40;             // LDS row stride (floats)
    constexpr int PLANE = 38 * LS;     // 1520 floats per padded slice
    __shared__ float sAll[7 * PLANE];  // plane 0: scaled batch; planes 1..6: preds k=0..5
    __shared__ float redBuf[8][6];     // per-wave {A0,A1,A2,V0,V1,V2} (kh-local)

    const int tid = threadIdx.x;
    const int bx  = blockIdx.x;
    const int b   = bx / 224;          // 8 batches
    const int r   = bx - b * 224;
    const int d   = r / 7;             // 32 d-slices
    const int dz  = r - d * 7;         // 7 window z-offsets

    const int z = d + dz - 3;
    const bool zok = (z >= 0) && (z < 32);

    // ---- init all planes to pad value (aligned f4 stores) ----
    {
        f4* b4 = (f4*)sAll;                    // 380 f4 (batch plane, scaled pad)
        const f4 bpad = {EPSV * SSCL, EPSV * SSCL, EPSV * SSCL, EPSV * SSCL};
        if (tid < 380) b4[tid] = bpad;
        f4* p4 = (f4*)(sAll + PLANE);          // 2280 f4 (pred planes)
        const f4 ppad = {EPSV, EPSV, EPSV, EPSV};
        for (int i = tid; i < 2280; i += 512) p4[i] = ppad;
    }
    __syncthreads();

    // ---- copy interiors: coalesced f4 loads, shifts/masks only (1792 = 7 planes * 256 tiles) ----
    if (zok) {
        const float* bsrc = batch + ((size_t)b * 32 + z) * 1024;
        const float* psrc = preds + ((size_t)b * 6 * 32 + z) * 1024;
        #pragma unroll
        for (int it = 0; it < 4; ++it) {
            int idx = tid + it * 512;
            if (idx < 1792) {
                int p  = idx >> 8;             // 0..6
                int r8 = idx & 255;
                int hh = r8 >> 3;              // 0..31
                int j4 = (r8 & 7) << 2;        // 0,4,...,28
                const float* src = (p == 0) ? (bsrc + hh * 32 + j4)
                                            : (psrc + (size_t)(p - 1) * 32768 + hh * 32 + j4);
                f4 v = *(const f4*)src;
                if (p == 0) v *= SSCL;
                float* dst = sAll + p * PLANE + (hh + 3) * LS + (j4 + 3);
                dst[0] = v.x; dst[1] = v.y; dst[2] = v.z; dst[3] = v.w;
            }
        }
    }

    // thread mapping for compute
    const int kh = tid >> 8;           // 0/1 -> classes 3kh..3kh+2 (wave-uniform)
    const int h  = (tid >> 3) & 31;    // row
    const int v0 = (tid & 7) << 2;     // voxel start (16B aligned)

    // center intensities (pre-scaled), overlap with staging
    f4 Ip = *(const f4*)&batch[((size_t)b * 32 + d) * 1024 + h * 32 + v0];
    Ip *= SSCL;

    __syncthreads();

    f4 wsum = {};
    f4 acc[3] = {};
    const int czz = (dz - 3) * (dz - 3);          // runtime scalar (from blockIdx)
    const float gz = (float)czz * C3F;
    const float* pbase = sAll + (size_t)(1 + 3 * kh) * PLANE;

    #pragma unroll
    for (int dy = 0; dy < 7; ++dy) {
        const int cyy = (dy - 3) * (dy - 3);      // compile-time
        if (czz + cyy >= 16) continue;            // scalar-uniform skip of whole row

        const int rowOff = (h + dy) * LS + v0;    // 8B-aligned
        // bseg: 10 floats via 5 x ds_read_b64 (conflict-light pattern)
        const f2* br = (const f2*)(sAll + rowOff);
        f2 t0 = br[0], t1 = br[1], t2 = br[2], t3 = br[3], t4 = br[4];
        float bseg[10] = {t0.x, t0.y, t1.x, t1.y, t2.x, t2.y, t3.x, t3.y, t4.x, t4.y};

        // weights for all in-ball dx (scalar-guarded); wv zero otherwise
        f4 wv[7] = {};
        #pragma unroll
        for (int dx = 0; dx < 7; ++dx) {
            const int cxx = (dx - 3) * (dx - 3);  // compile-time
            if (czz + cyy + cxx < 16) {           // scalar-uniform branch
                const float g = gz + (float)(cyy + cxx) * C3F;
                f4 bv = {bseg[dx], bseg[dx + 1], bseg[dx + 2], bseg[dx + 3]};
                f4 dI = Ip - bv;
                f4 t  = (f4){g, g, g, g} - dI * dI;
                f4 w;
                w.x = __builtin_amdgcn_exp2f(t.x);
                w.y = __builtin_amdgcn_exp2f(t.y);
                w.z = __builtin_amdgcn_exp2f(t.z);
                w.w = __builtin_amdgcn_exp2f(t.w);
                wv[dx] = w;
                wsum += w;
            }
        }

        // stream 3 pred planes: 5 b64 each, guarded FMAs
        #pragma unroll
        for (int kk = 0; kk < 3; ++kk) {
            const f2* pr = (const f2*)(pbase + kk * PLANE + rowOff);
            f2 q0 = pr[0], q1 = pr[1], q2 = pr[2], q3 = pr[3], q4 = pr[4];
            float pseg[10] = {q0.x, q0.y, q1.x, q1.y, q2.x, q2.y, q3.x, q3.y, q4.x, q4.y};
            f4 a = acc[kk];
            #pragma unroll
            for (int dx = 0; dx < 7; ++dx) {
                const int cxx = (dx - 3) * (dx - 3);
                if (czz + cyy + cxx < 16)
                    a += wv[dx] * (f4){pseg[dx], pseg[dx + 1], pseg[dx + 2], pseg[dx + 3]};
            }
            acc[kk] = a;
        }
    }

    // fold in center preds: A_k = <acc_kk, predC_k>, V_k = <wsum, predC_k>, k = 3kh+kk
    float pA[3], pV[3];
    #pragma unroll
    for (int kk = 0; kk < 3; ++kk) {
        const int k = 3 * kh + kk;
        const size_t pc = (((size_t)b * 6 + k) * 32 + d) * 1024 + h * 32 + v0;
        f4 pcv = *(const f4*)&preds[pc];
        pA[kk] = acc[kk].x * pcv.x + acc[kk].y * pcv.y + acc[kk].z * pcv.z + acc[kk].w * pcv.w;
        pV[kk] = wsum.x * pcv.x + wsum.y * pcv.y + wsum.z * pcv.z + wsum.w * pcv.w;
    }

    // wave reduction (64 lanes; kh is wave-uniform)
    #pragma unroll
    for (int kk = 0; kk < 3; ++kk) {
        #pragma unroll
        for (int off = 32; off > 0; off >>= 1) {
            pA[kk] += __shfl_down(pA[kk], off);
            pV[kk] += __shfl_down(pV[kk], off);
        }
    }
    const int lane = tid & 63, wave = tid >> 6;   // waves 0-3: kh=0, waves 4-7: kh=1
    if (lane == 0) {
        #pragma unroll
        for (int kk = 0; kk < 3; ++kk) {
            redBuf[wave][kk]     = pA[kk];
            redBuf[wave][3 + kk] = pV[kk];
        }
    }
    __syncthreads();
    if (tid < 12) {
        const int isV = (tid >= 6);
        const int k   = isV ? (tid - 6) : tid;    // 0..5
        const int wq  = (k / 3) * 4;              // source wave quad
        const int c   = (k % 3) + (isV ? 3 : 0);
        float s = redBuf[wq][c] + redBuf[wq + 1][c] + redBuf[wq + 2][c] + redBuf[wq + 3][c];
        if (!isV) wsA[bx * 6 + k] = s;
        else      wsV[bx * 6 + k] = s;
    }
}

// Reduce 224 partials per batch, form 6 - sum_k A_k/V_k
__global__ __launch_bounds__(256) void ncut_final(const float* __restrict__ wsA,
                                                  const float* __restrict__ wsV,
                                                  float* __restrict__ out) {
    __shared__ float redBuf[4][12];
    const int b = blockIdx.x;
    const int t = threadIdx.x;
    float a[6] = {}, v[6] = {};
    if (t < 224) {
        #pragma unroll
        for (int k = 0; k < 6; ++k) {
            a[k] = wsA[((size_t)b * 224 + t) * 6 + k];
            v[k] = wsV[((size_t)b * 224 + t) * 6 + k];
        }
    }
    #pragma unroll
    for (int k = 0; k < 6; ++k) {
        #pragma unroll
        for (int off = 32; off > 0; off >>= 1) {
            a[k] += __shfl_down(a[k], off);
            v[k] += __shfl_down(v[k], off);
        }
    }
    const int lane = t & 63, wave = t >> 6;
    if (lane == 0) {
        #pragma unroll
        for (int k = 0; k < 6; ++k) {
            redBuf[wave][k] = a[k];
            redBuf[wave][6 + k] = v[k];
        }
    }
    __syncthreads();
    if (t == 0) {
        float s = 0.f;
        #pragma unroll
        for (int k = 0; k < 6; ++k) {
            float sa = redBuf[0][k] + redBuf[1][k] + redBuf[2][k] + redBuf[3][k];
            float sv = redBuf[0][6 + k] + redBuf[1][6 + k] + redBuf[2][6 + k] + redBuf[3][6 + k];
            s += sa / sv;
        }
        out[b] = 6.0f - s;
    }
}

extern "C" void kernel_launch(void* const* d_in, const int* in_sizes, int n_in,
                              void* d_out, int out_size, void* d_ws, size_t ws_size,
                              hipStream_t stream) {
    const float* batch = (const float*)d_in[0];   // 8*1*32^3
    const float* preds = (const float*)d_in[1];   // 8*6*32^3
    float* out = (float*)d_out;                   // 8 floats
    float* wsA = (float*)d_ws;                    // 1792*6 floats
    float* wsV = wsA + 1792 * 6;                  // 1792*6 floats

    ncut_main<<<1792, 512, 0, stream>>>(batch, preds, wsA, wsV);
    ncut_final<<<8, 256, 0, stream>>>(wsA, wsV, out);
}

// Round 7
// 50.718 us; speedup vs baseline: 1.1160x; 1.1160x over previous
//
#include <hip/hip_runtime.h>

#define EPSV 2.220446049250313e-16f
#define C3F  (-0.09016844005555896f)   // -log2(e)/16
#define SSCL 0.1201122408786449f       // sqrt(log2(e)/100); (SSCL*dI)^2 = dI^2*log2(e)/100

typedef float f2 __attribute__((ext_vector_type(2)));
typedef float f4 __attribute__((ext_vector_type(4)));

// batch: (8,1,32,32,32) f32 ; preds: (8,6,32,32,32) f32 ; out: (8,) f32
// PAD=3, WIN=7. w(p,off) = exp2(g - (s*dI)^2), g = -d2*log2e/16, zero outside ball d2<16.
// Grid: (b,d,dz) = 1792 blocks, 512 threads.
// dy-split: waves 0-3 (tid<256) handle dy 0..3; waves 4-7 handle dy 4..6.
// Each thread: 4 voxels (quad), all 6 classes. Weight computed once per (voxel,dy,dx).
// LS=38: row bank-shift 6 => b64 starts cover 16 banks x 4 lanes -> conflict-free.

__global__ __launch_bounds__(512, 6) void ncut_main(const float* __restrict__ batch,
                                                    const float* __restrict__ preds,
                                                    float* __restrict__ wsA,
                                                    float* __restrict__ wsV) {
    constexpr int LS = 38;             // LDS row stride (floats)
    constexpr int PLANE = 38 * LS;     // 1444 floats per padded slice
    __shared__ float sAll[7 * PLANE];  // plane 0: scaled batch; planes 1..6: preds k=0..5
    __shared__ float redBuf[8][12];

    const int tid = threadIdx.x;
    const int bx  = blockIdx.x;
    const int b   = bx / 224;          // 8 batches
    const int r   = bx - b * 224;
    const int d   = r / 7;             // 32 d-slices
    const int dz  = r - d * 7;         // 7 window z-offsets

    const int z = d + dz - 3;
    const bool zok = (z >= 0) && (z < 32);

    // ---- init all planes to pad value (aligned f4 stores; 7*1444/4 = 2527 f4) ----
    {
        f4* a4 = (f4*)sAll;
        const f4 bpad = {EPSV * SSCL, EPSV * SSCL, EPSV * SSCL, EPSV * SSCL};
        const f4 ppad = {EPSV, EPSV, EPSV, EPSV};
        for (int i = tid; i < 2527; i += 512) a4[i] = (i < 361) ? bpad : ppad;
    }
    __syncthreads();

    // ---- copy interiors: coalesced f4 loads, shifts/masks only (1792 = 7 planes * 256 tiles) ----
    if (zok) {
        const float* bsrc = batch + ((size_t)b * 32 + z) * 1024;
        const float* psrc = preds + ((size_t)b * 6 * 32 + z) * 1024;
        #pragma unroll
        for (int it = 0; it < 4; ++it) {
            int idx = tid + it * 512;
            if (idx < 1792) {
                int p  = idx >> 8;             // 0..6
                int r8 = idx & 255;
                int hh = r8 >> 3;              // 0..31
                int j4 = (r8 & 7) << 2;        // 0,4,...,28
                const float* src = (p == 0) ? (bsrc + hh * 32 + j4)
                                            : (psrc + (size_t)(p - 1) * 32768 + hh * 32 + j4);
                f4 v = *(const f4*)src;
                if (p == 0) v *= SSCL;
                float* dst = sAll + p * PLANE + (hh + 3) * LS + (j4 + 3);
                dst[0] = v.x; dst[1] = v.y; dst[2] = v.z; dst[3] = v.w;
            }
        }
    }

    // thread mapping for compute
    const int dyg = tid >> 8;          // 0: dy 0..3, 1: dy 4..6 (wave-uniform)
    const int h   = (tid >> 3) & 31;   // row
    const int v0  = (tid & 7) << 2;    // voxel start

    // center intensities (pre-scaled), overlap with staging
    f4 Ip = *(const f4*)&batch[((size_t)b * 32 + d) * 1024 + h * 32 + v0];
    Ip *= SSCL;

    __syncthreads();

    f4 wsum = {};
    f4 acc[6] = {};
    const int czz = (dz - 3) * (dz - 3);          // runtime scalar (from blockIdx)
    const float gz = (float)czz * C3F;

    #pragma unroll
    for (int dy = 0; dy < 7; ++dy) {
        // scalar-uniform: this wave-group's dy range
        if ((dy < 4) ? (dyg != 0) : (dyg != 1)) continue;
        const int cyy = (dy - 3) * (dy - 3);      // compile-time
        if (czz + cyy >= 16) continue;            // scalar-uniform ball skip (whole row)

        const int rowOff = (h + dy) * LS + v0;    // even -> 8B aligned
        // bseg: 10 floats via 5 x ds_read_b64 (conflict-free with LS=38)
        const f2* br = (const f2*)(sAll + rowOff);
        f2 t0 = br[0], t1 = br[1], t2 = br[2], t3 = br[3], t4 = br[4];
        float bseg[10] = {t0.x, t0.y, t1.x, t1.y, t2.x, t2.y, t3.x, t3.y, t4.x, t4.y};

        // weights for in-ball dx (scalar-guarded); wv zero otherwise
        f4 wv[7] = {};
        #pragma unroll
        for (int dx = 0; dx < 7; ++dx) {
            const int cxx = (dx - 3) * (dx - 3);  // compile-time
            if (czz + cyy + cxx < 16) {           // scalar-uniform branch
                const float g = gz + (float)(cyy + cxx) * C3F;
                f4 bv = {bseg[dx], bseg[dx + 1], bseg[dx + 2], bseg[dx + 3]};
                f4 dI = Ip - bv;
                f4 t  = (f4){g, g, g, g} - dI * dI;
                f4 w;
                w.x = __builtin_amdgcn_exp2f(t.x);
                w.y = __builtin_amdgcn_exp2f(t.y);
                w.z = __builtin_amdgcn_exp2f(t.z);
                w.w = __builtin_amdgcn_exp2f(t.w);
                wv[dx] = w;
                wsum += w;
            }
        }

        // stream 6 pred planes: 5 b64 each, guarded FMAs
        #pragma unroll
        for (int k = 0; k < 6; ++k) {
            const f2* pr = (const f2*)(sAll + (k + 1) * PLANE + rowOff);
            f2 q0 = pr[0], q1 = pr[1], q2 = pr[2], q3 = pr[3], q4 = pr[4];
            float pseg[10] = {q0.x, q0.y, q1.x, q1.y, q2.x, q2.y, q3.x, q3.y, q4.x, q4.y};
            f4 a = acc[k];
            #pragma unroll
            for (int dx = 0; dx < 7; ++dx) {
                const int cxx = (dx - 3) * (dx - 3);
                if (czz + cyy + cxx < 16)
                    a += wv[dx] * (f4){pseg[dx], pseg[dx + 1], pseg[dx + 2], pseg[dx + 3]};
            }
            acc[k] = a;
        }
    }

    // fold in center preds: A_k = <acc_k, predC_k>, V_k = <wsum, predC_k>
    float pA[6], pV[6];
    #pragma unroll
    for (int k = 0; k < 6; ++k) {
        const size_t pc = (((size_t)b * 6 + k) * 32 + d) * 1024 + h * 32 + v0;
        f4 pcv = *(const f4*)&preds[pc];
        pA[k] = acc[k].x * pcv.x + acc[k].y * pcv.y + acc[k].z * pcv.z + acc[k].w * pcv.w;
        pV[k] = wsum.x * pcv.x + wsum.y * pcv.y + wsum.z * pcv.z + wsum.w * pcv.w;
    }

    // wave reduction (64 lanes)
    #pragma unroll
    for (int k = 0; k < 6; ++k) {
        #pragma unroll
        for (int off = 32; off > 0; off >>= 1) {
            pA[k] += __shfl_down(pA[k], off);
            pV[k] += __shfl_down(pV[k], off);
        }
    }
    const int lane = tid & 63, wave = tid >> 6;
    if (lane == 0) {
        #pragma unroll
        for (int k = 0; k < 6; ++k) {
            redBuf[wave][k]     = pA[k];
            redBuf[wave][6 + k] = pV[k];
        }
    }
    __syncthreads();
    if (tid < 12) {
        float s = 0.f;
        #pragma unroll
        for (int wv8 = 0; wv8 < 8; ++wv8) s += redBuf[wv8][tid];
        if (tid < 6) wsA[bx * 6 + tid] = s;
        else         wsV[bx * 6 + (tid - 6)] = s;
    }
}

// Reduce 224 partials per batch, form 6 - sum_k A_k/V_k
__global__ __launch_bounds__(256) void ncut_final(const float* __restrict__ wsA,
                                                  const float* __restrict__ wsV,
                                                  float* __restrict__ out) {
    __shared__ float redBuf[4][12];
    const int b = blockIdx.x;
    const int t = threadIdx.x;
    float a[6] = {}, v[6] = {};
    if (t < 224) {
        #pragma unroll
        for (int k = 0; k < 6; ++k) {
            a[k] = wsA[((size_t)b * 224 + t) * 6 + k];
            v[k] = wsV[((size_t)b * 224 + t) * 6 + k];
        }
    }
    #pragma unroll
    for (int k = 0; k < 6; ++k) {
        #pragma unroll
        for (int off = 32; off > 0; off >>= 1) {
            a[k] += __shfl_down(a[k], off);
            v[k] += __shfl_down(v[k], off);
        }
    }
    const int lane = t & 63, wave = t >> 6;
    if (lane == 0) {
        #pragma unroll
        for (int k = 0; k < 6; ++k) {
            redBuf[wave][k] = a[k];
            redBuf[wave][6 + k] = v[k];
        }
    }
    __syncthreads();
    if (t == 0) {
        float s = 0.f;
        #pragma unroll
        for (int k = 0; k < 6; ++k) {
            float sa = redBuf[0][k] + redBuf[1][k] + redBuf[2][k] + redBuf[3][k];
            float sv = redBuf[0][6 + k] + redBuf[1][6 + k] + redBuf[2][6 + k] + redBuf[3][6 + k];
            s += sa / sv;
        }
        out[b] = 6.0f - s;
    }
}

extern "C" void kernel_launch(void* const* d_in, const int* in_sizes, int n_in,
                              void* d_out, int out_size, void* d_ws, size_t ws_size,
                              hipStream_t stream) {
    const float* batch = (const float*)d_in[0];   // 8*1*32^3
    const float* preds = (const float*)d_in[1];   // 8*6*32^3
    float* out = (float*)d_out;                   // 8 floats
    float* wsA = (float*)d_ws;                    // 1792*6 floats
    float* wsV = wsA + 1792 * 6;                  // 1792*6 floats

    ncut_main<<<1792, 512, 0, stream>>>(batch, preds, wsA, wsV);
    ncut_final<<<8, 256, 0, stream>>>(wsA, wsV, out);
}